// Round 6
// baseline (233.152 us; speedup 1.0000x reference)
//
#include <hip/hip_runtime.h>
#include <hip/hip_fp16.h>

// Problem constants
#define B_     8
#define NCAM   5
#define J_     15
#define H_     128
#define W_     240
#define NB     128000             // bins = 80*80*20
#define HW_    (H_ * W_)          // 30720
// x-pair f16 image: dword[y*W+x] = (f16 v(y,x), f16 v(y,x+1)); col x=239 garbage/unread.
// One bilinear sample = ONE ds_read2_b32: rows yc (off 0) and yc+1 (off 240 dwords).
#define IMG_DW   HW_              // 30720 dwords
#define SMEM_BYTES (IMG_DW * 4)   // 122880 B -> 1 block/CU, 16 waves
#define IMG_G4   (IMG_DW / 4)     // 7680 uint4 groups
#define TPB    1024
#define NCHUNK 8                  // 960 blocks
#define BPB    (NB / NCHUNK)      // 16000 bins per block
#define ITEMS  16                 // ceil(16000/1024); last iter guarded
#define NBJ    (B_ * J_)          // 120
#define NBLK   (NBJ * NCHUNK)     // 960

typedef __fp16 fp16x2 __attribute__((ext_vector_type(2)));

__device__ __forceinline__ unsigned int pkrtz(float lo, float hi) {
    fp16x2 h = __builtin_amdgcn_cvt_pkrtz(lo, hi);  // v_cvt_pkrtz_f16_f32
    return __builtin_bit_cast(unsigned int, h);
}

// Bilinear weights, padding_mode='zeros' validity folded into clamped 2x2
// window (validated R1-R5). Camera-mean 1/5 folded into weights.
// Row-grouped for the x-pair image:
//   addr16 = yc*W + xc  (<= 30478, fits u16)
//   wtop = (0.2*b0*a0, 0.2*b0*a1)   -- row yc,   cols (xc, xc+1)
//   wbot = (0.2*b1*a0, 0.2*b1*a1)   -- row yc+1
__device__ __forceinline__ void bilinear_rec(float gx, float gy,
                                             unsigned int& addr,
                                             unsigned int& wtop,
                                             unsigned int& wbot) {
    const float ix = (gx + 1.0f) * (0.5f * (W_ - 1));
    const float iy = (gy + 1.0f) * (0.5f * (H_ - 1));
    const float x0f = floorf(ix);
    const float y0f = floorf(iy);
    const float wx1 = ix - x0f, wx0 = 1.0f - wx1;
    const float wy1 = iy - y0f, wy0 = 1.0f - wy1;
    const int x0 = (int)x0f;
    const int y0 = (int)y0f;
    const int xc = min(max(x0, 0), W_ - 2);
    const int yc = min(max(y0, 0), H_ - 2);
    const float vx0 = (x0 >= 0  && x0 <= W_ - 1) ? wx0 : 0.0f;
    const float vx1 = (x0 >= -1 && x0 <= W_ - 2) ? wx1 : 0.0f;
    const float vy0 = (y0 >= 0  && y0 <= H_ - 1) ? wy0 : 0.0f;
    const float vy1 = (y0 >= -1 && y0 <= H_ - 2) ? wy1 : 0.0f;
    const bool xhi = (x0 == W_ - 1);
    const bool xlo = (x0 == -1);
    const bool yhi = (y0 == H_ - 1);
    const bool ylo = (y0 == -1);
    const float a0 = (xhi ? 0.0f : vx0) + (xlo ? vx1 : 0.0f);
    const float a1 = (xhi ? vx0 : 0.0f) + (xlo ? 0.0f : vx1);
    const float b0 = (yhi ? 0.0f : vy0) + (ylo ? vy1 : 0.0f);
    const float b1 = (yhi ? vy0 : 0.0f) + (ylo ? 0.0f : vy1);
    addr = (unsigned int)(yc * W_ + xc);
    wtop = pkrtz(0.2f * (b0 * a0), 0.2f * (b0 * a1));
    wbot = pkrtz(0.2f * (b1 * a0), 0.2f * (b1 * a1));
}

__global__ __launch_bounds__(256) void weights_kernel(
    const float* __restrict__ sgrid,          // [NCAM, NB, 2]
    unsigned short* __restrict__ addr16,      // [NCAM*NB]
    uint2* __restrict__ wpk)                  // [NCAM*NB] = (wtop, wbot)
{
    const int i = blockIdx.x * 256 + threadIdx.x;
    if (i >= NCAM * NB) return;
    const float2 g = ((const float2*)sgrid)[i];
    unsigned int a, wt, wb;
    bilinear_rec(g.x, g.y, a, wt, wb);
    addr16[i] = (unsigned short)a;
    wpk[i] = make_uint2(wt, wb);
}

// Stage f32 image as x-pair f16 dwords: d[i] = pk(v[i], v[i+1]) over flat i.
// (Row stride 240 % 4 == 0; the x=239 column pairs with next row's col 0 --
//  garbage but never read. Clamp the one-past-image element.)
__device__ __forceinline__ void stage_xpairs(const float* __restrict__ img,
                                             unsigned int* s_img, int tid) {
    const float4* __restrict__ src4 = (const float4*)img;
    uint4* dst = (uint4*)s_img;
    for (int g = tid; g < IMG_G4; g += TPB) {
        const float4 a = src4[g];
        const float  b = img[min(4 * g + 4, HW_ - 1)];  // next element (clamped at end)
        uint4 d;
        d.x = pkrtz(a.x, a.y);
        d.y = pkrtz(a.y, a.z);
        d.z = pkrtz(a.z, a.w);
        d.w = pkrtz(a.w, b);
        dst[g] = d;
    }
}

// One bilinear sample: single ds_read2_b32 (rows yc, yc+1), two packed f16 FMAs.
__device__ __forceinline__ float sample_xpair(const unsigned int* s_img,
                                              unsigned int a,
                                              unsigned int wtop, unsigned int wbot) {
    const unsigned int* base = s_img + a;
    const unsigned int d_top = base[0];     // (v00, v01)   } ds_read2_b32
    const unsigned int d_bot = base[W_];    // (v10, v11)   } offset1:240
    __half2 p = __hmul2(__builtin_bit_cast(__half2, d_top),
                        __builtin_bit_cast(__half2, wtop));
    p = __hfma2(__builtin_bit_cast(__half2, d_bot),
                __builtin_bit_cast(__half2, wbot), p);
    return __low2float(p) + __high2float(p);
}

__global__ __launch_bounds__(TPB, 4) void project_kernel(
    const float* __restrict__ hm,             // [B, NCAM, J, H, W]
    const unsigned short* __restrict__ addr16,
    const uint2* __restrict__ wpk,
    float* __restrict__ out)                  // [B, J, NB]
{
    extern __shared__ unsigned int s_img[];   // IMG_DW dwords
    const int tid   = threadIdx.x;
    // bj-major: same-bj blocks at bids bj+120k; 120%8==0 -> same XCD -> L2 reuse.
    const int bj    = blockIdx.x % NBJ;
    const int chunk = blockIdx.x / NBJ;
    const int b     = bj / J_;
    const int j     = bj % J_;
    const int bin0  = chunk * BPB;

    float acc[ITEMS];
#pragma unroll
    for (int it = 0; it < ITEMS; ++it) acc[it] = 0.0f;

    for (int n = 0; n < NCAM; ++n) {
        __syncthreads();
        stage_xpairs(hm + (((size_t)b * NCAM + n) * J_ + j) * HW_, s_img, tid);
        __syncthreads();
        const unsigned short* __restrict__ ap = addr16 + n * NB + bin0;
        const uint2* __restrict__ wp = wpk + n * NB + bin0;
#pragma unroll
        for (int it = 0; it < ITEMS; ++it) {
            const int r = it * TPB + tid;     // coalesced
            if (r < BPB) {                    // only it==15 is partial (16000=15*1024+640)
                acc[it] += sample_xpair(s_img, ap[r], wp[r].x, wp[r].y);
            }
        }
    }

    float* __restrict__ o = out + (size_t)bj * NB + bin0;
#pragma unroll
    for (int it = 0; it < ITEMS; ++it) {
        const int r = it * TPB + tid;
        if (r < BPB) o[r] = fminf(fmaxf(acc[it], 0.0f), 1.0f);  // 1/5 in weights
    }
}

// Fallback (tiny ws): R1-style f32-LDS kernel, inline weights. 600 blocks.
#define FB_SMEM   (HW_ * 4)
#define FB_NCHUNK 5
#define FB_BPB    (NB / FB_NCHUNK)   // 25600
#define FB_ITEMS  (FB_BPB / TPB)     // 25
__global__ __launch_bounds__(TPB) void project_fallback(
    const float* __restrict__ hm,
    const float* __restrict__ sgrid,
    float* __restrict__ out)
{
    extern __shared__ float s_f32[];
    const int tid   = threadIdx.x;
    const int bj    = blockIdx.x % NBJ;
    const int chunk = blockIdx.x / NBJ;
    const int b     = bj / J_;
    const int j     = bj % J_;
    const int bin0  = chunk * FB_BPB;

    float acc[FB_ITEMS];
#pragma unroll
    for (int it = 0; it < FB_ITEMS; ++it) acc[it] = 0.0f;

    for (int n = 0; n < NCAM; ++n) {
        __syncthreads();
        const float4* __restrict__ src =
            (const float4*)(hm + (((size_t)b * NCAM + n) * J_ + j) * HW_);
        float4* dst = (float4*)s_f32;
        for (int i = tid; i < HW_ / 4; i += TPB) dst[i] = src[i];
        __syncthreads();
        const float2* __restrict__ g2 = (const float2*)sgrid + n * NB + bin0;
#pragma unroll
        for (int it = 0; it < FB_ITEMS; ++it) {
            const float2 g = g2[it * TPB + tid];
            const float ix = (g.x + 1.0f) * (0.5f * (W_ - 1));
            const float iy = (g.y + 1.0f) * (0.5f * (H_ - 1));
            const float x0f = floorf(ix), y0f = floorf(iy);
            const float wx1 = ix - x0f, wx0 = 1.0f - wx1;
            const float wy1 = iy - y0f, wy0 = 1.0f - wy1;
            const int x0 = (int)x0f, y0 = (int)y0f;
            const int xc = min(max(x0, 0), W_ - 2);
            const int yc = min(max(y0, 0), H_ - 2);
            const float vx0 = (x0 >= 0  && x0 <= W_ - 1) ? wx0 : 0.0f;
            const float vx1 = (x0 >= -1 && x0 <= W_ - 2) ? wx1 : 0.0f;
            const float vy0 = (y0 >= 0  && y0 <= H_ - 1) ? wy0 : 0.0f;
            const float vy1 = (y0 >= -1 && y0 <= H_ - 2) ? wy1 : 0.0f;
            const bool xhi = (x0 == W_ - 1), xlo = (x0 == -1);
            const bool yhi = (y0 == H_ - 1), ylo = (y0 == -1);
            const float a0 = (xhi ? 0.0f : vx0) + (xlo ? vx1 : 0.0f);
            const float a1 = (xhi ? vx0 : 0.0f) + (xlo ? 0.0f : vx1);
            const float b0 = (yhi ? 0.0f : vy0) + (ylo ? vy1 : 0.0f);
            const float b1 = (yhi ? vy0 : 0.0f) + (ylo ? 0.0f : vy1);
            const float* r0 = s_f32 + (yc * W_ + xc);
            acc[it] += b0 * (a0 * r0[0] + a1 * r0[1])
                     + b1 * (a0 * r0[W_] + a1 * r0[W_ + 1]);
        }
    }
    float* __restrict__ o = out + (size_t)bj * NB + bin0;
#pragma unroll
    for (int it = 0; it < FB_ITEMS; ++it)
        o[it * TPB + tid] = fminf(fmaxf(acc[it] * 0.2f, 0.0f), 1.0f);
}

extern "C" void kernel_launch(void* const* d_in, const int* in_sizes, int n_in,
                              void* d_out, int out_size, void* d_ws, size_t ws_size,
                              hipStream_t stream) {
    const float* hm = (const float*)d_in[0];   // [8,5,15,128,240] f32
    const float* sg = (const float*)d_in[1];   // [5,128000,2] f32
    float* out = (float*)d_out;                // [8,15,128000] f32

    (void)hipFuncSetAttribute((const void*)project_kernel,
                              hipFuncAttributeMaxDynamicSharedMemorySize, SMEM_BYTES);
    (void)hipFuncSetAttribute((const void*)project_fallback,
                              hipFuncAttributeMaxDynamicSharedMemorySize, FB_SMEM);

    const size_t addr_bytes = (size_t)NCAM * NB * sizeof(unsigned short); // 1.28 MB
    const size_t wpk_bytes  = (size_t)NCAM * NB * sizeof(uint2);          // 5.12 MB
    if (ws_size >= addr_bytes + wpk_bytes) {
        unsigned short* addr16 = (unsigned short*)d_ws;
        uint2* wpk = (uint2*)((char*)d_ws + addr_bytes);
        weights_kernel<<<(NCAM * NB + 255) / 256, 256, 0, stream>>>(sg, addr16, wpk);
        project_kernel<<<NBLK, TPB, SMEM_BYTES, stream>>>(hm, addr16, wpk, out);
    } else {
        project_fallback<<<NBJ * FB_NCHUNK, TPB, FB_SMEM, stream>>>(hm, sg, out);
    }
}